// Round 1
// baseline (15248.520 us; speedup 1.0000x reference)
//
#include <hip/hip_runtime.h>
#include <hip/hip_bf16.h>

#define DEV static __device__ __forceinline__

// ---------------- helpers ----------------
DEV float wred(float v) {
#pragma unroll
  for (int off = 32; off > 0; off >>= 1) v += __shfl_down(v, off, 64);
  return v;
}

DEV unsigned short f2bf(float f) {
  union { float f; unsigned u; } a; a.f = f;
  unsigned u = a.u;
  unsigned lsb = (u >> 16) & 1u;
  u += 0x7fffu + lsb;            // round-to-nearest-even
  return (unsigned short)(u >> 16);
}
DEV float bf2f(unsigned short us) {
  union { unsigned u; float f; } a; a.u = ((unsigned)us) << 16;
  return a.f;
}

// ---------------- ws layout (bytes) ----------------
// peak ~157 MB
#define OFF_OUT1   ((size_t)0)           // bf16 [64,64,112,112] = 102,760,448 B
#define OFF_OUT2   ((size_t)0)           // f32  [64,128,28,28]  (reuses OUT1 after pool1)
#define OFF_POOL2  ((size_t)25690112)    // f32  [64,128,14,14]
#define OFF_W2     ((size_t)32112640)    // f32  [64,128,64,3,3]
#define OFF_L1PRE  ((size_t)50987008)    // f32  [64,256,7,7]
#define OFF_L1     ((size_t)54198272)
#define OFF_L2PRE  ((size_t)57409536)
#define OFF_RPRE   ((size_t)60620800)
#define OFF_RES    ((size_t)63832064)
#define OFF_POOL1  ((size_t)102760448)   // f32  [64,64,56,56] = 51,380,224 B
#define OFF_W1     ((size_t)154140672)   // f32  [64,64,3,7,7]
#define OFF_STATS  ((size_t)156549120)   // 1920 f32
#define OFF_ATTN1  (OFF_STATS + 8192)
#define OFF_ATTN2  (OFF_ATTN1 + 2048)
#define OFF_XBAR   (OFF_ATTN2 + 2048)    // [64,256] f32
#define OFF_U      (OFF_XBAR + 65536)    // [64,1024] f32

// stats float indices
#define S1_SUM 0
#define S1_SQ  64
#define S2_SUM 128
#define S2_SQ  256
#define R1_SUM 384
#define R1_SQ  640
#define R2_SUM 896
#define R2_SQ  1152
#define RS_SUM 1408
#define RS_SQ  1664
#define STATS_N 1920

// ---------------- attention MLPs ----------------
__global__ void attn1_kernel(const float* __restrict__ imgs,
                             const float* __restrict__ fc1w,   // [8,3]
                             const float* __restrict__ fc2w,   // [8,8]
                             const float* __restrict__ fc2b,   // [8]
                             float* __restrict__ attn) {       // [64,8]
  int b = blockIdx.x, tid = threadIdx.x, wid = tid >> 6, lane = tid & 63;
  __shared__ float pooled[3];
  const float* x = imgs + (size_t)b * 150528;
  if (wid < 3) {
    const float* src = x + wid * 50176;
    float s = 0.f;
    for (int i = lane; i < 50176; i += 64) s += src[i];
    s = wred(s);
    if (lane == 0) pooled[wid] = s * (1.f / 50176.f);
  }
  __syncthreads();
  if (tid == 0) {
    float h[8];
#pragma unroll
    for (int j = 0; j < 8; ++j) {
      float a = fc1w[j*3+0]*pooled[0] + fc1w[j*3+1]*pooled[1] + fc1w[j*3+2]*pooled[2];
      h[j] = a > 0.f ? a : 0.f;
    }
    float lg[8], mx = -1e30f;
#pragma unroll
    for (int k = 0; k < 8; ++k) {
      float a = fc2b[k];
#pragma unroll
      for (int j = 0; j < 8; ++j) a = fmaf(fc2w[k*8+j], h[j], a);
      lg[k] = a; mx = fmaxf(mx, a);
    }
    float den = 0.f;
#pragma unroll
    for (int k = 0; k < 8; ++k) { lg[k] = expf(lg[k]-mx); den += lg[k]; }
    float inv = 1.f/den;
#pragma unroll
    for (int k = 0; k < 8; ++k) attn[b*8+k] = lg[k]*inv;
  }
}

__global__ void attn2_kernel(const float* __restrict__ pool1,
                             const float* __restrict__ fc1w,   // [17,64]
                             const float* __restrict__ fc2w,   // [8,17]
                             const float* __restrict__ fc2b,   // [8]
                             float* __restrict__ attn) {       // [64,8]
  int b = blockIdx.x, tid = threadIdx.x, wid = tid >> 6, lane = tid & 63;
  __shared__ float pooled[64];
  const float* x = pool1 + (size_t)b * 64 * 3136;
  for (int c = wid; c < 64; c += 4) {
    const float* src = x + (size_t)c * 3136;
    float s = 0.f;
    for (int i = lane; i < 3136; i += 64) s += src[i];
    s = wred(s);
    if (lane == 0) pooled[c] = s * (1.f/3136.f);
  }
  __syncthreads();
  if (tid == 0) {
    float h[17];
    for (int j = 0; j < 17; ++j) {
      float a = 0.f;
      for (int c = 0; c < 64; ++c) a = fmaf(fc1w[j*64+c], pooled[c], a);
      h[j] = a > 0.f ? a : 0.f;
    }
    float lg[8], mx = -1e30f;
    for (int k = 0; k < 8; ++k) {
      float a = fc2b[k];
      for (int j = 0; j < 17; ++j) a = fmaf(fc2w[k*17+j], h[j], a);
      lg[k] = a; mx = fmaxf(mx, a);
    }
    float den = 0.f;
    for (int k = 0; k < 8; ++k) { lg[k] = expf(lg[k]-mx); den += lg[k]; }
    float inv = 1.f/den;
    for (int k = 0; k < 8; ++k) attn[b*8+k] = lg[k]*inv;
  }
}

// w[b,i] = sum_k attn[b,k] * dyw[k,i]
__global__ void agg_w_kernel(const float* __restrict__ attn, const float* __restrict__ dyw,
                             float* __restrict__ w, int per) {
  int b = blockIdx.y;
  int i = blockIdx.x * 256 + threadIdx.x;
  if (i >= per) return;
  float s = 0.f;
#pragma unroll
  for (int k = 0; k < 8; ++k) s = fmaf(attn[b*8+k], dyw[(size_t)k*per + i], s);
  w[(size_t)b*per + i] = s;
}

// ---------------- conv1: [3,224,224] -> [64,112,112], k7 s2 p3, per-sample W ----------------
__global__ __launch_bounds__(256) void conv1_kernel(
    const float* __restrict__ imgs, const float* __restrict__ w1,
    unsigned short* __restrict__ out1, float* __restrict__ stats) {
  int oc = blockIdx.x, b = blockIdx.y;
  __shared__ float wsm[147];
  __shared__ float ssum[4], ssq[4];
  const float* wp = w1 + ((size_t)b*64 + oc) * 147;
  for (int i = threadIdx.x; i < 147; i += 256) wsm[i] = wp[i];
  __syncthreads();
  const float* in = imgs + (size_t)b * 150528;
  unsigned short* op = out1 + ((size_t)b*64 + oc) * 12544;
  float lsum = 0.f, lsq = 0.f;
  for (int g = threadIdx.x; g < 3136; g += 256) {
    int oy = g / 28;
    int ox0 = (g - oy*28) * 4;
    int iy0 = oy*2 - 3, ix0 = ox0*2 - 3;
    float a0=0.f, a1=0.f, a2=0.f, a3=0.f;
    if (oy >= 2 && oy <= 110 && ox0 >= 2 && ox0 <= 107) {
#pragma unroll
      for (int c = 0; c < 3; ++c) {
        const float* bc = in + c*50176 + iy0*224 + ix0;
#pragma unroll
        for (int ky = 0; ky < 7; ++ky) {
          const float* br = bc + ky*224;
          float r[13];
#pragma unroll
          for (int i = 0; i < 13; ++i) r[i] = br[i];
#pragma unroll
          for (int kx = 0; kx < 7; ++kx) {
            float wv = wsm[c*49 + ky*7 + kx];
            a0 = fmaf(r[kx],   wv, a0);
            a1 = fmaf(r[kx+2], wv, a1);
            a2 = fmaf(r[kx+4], wv, a2);
            a3 = fmaf(r[kx+6], wv, a3);
          }
        }
      }
    } else {
      float acc[4];
#pragma unroll
      for (int j = 0; j < 4; ++j) {
        int ixb = ix0 + 2*j;
        float a = 0.f;
        for (int c = 0; c < 3; ++c) {
          for (int ky = 0; ky < 7; ++ky) {
            int iy = iy0 + ky;
            if ((unsigned)iy >= 224u) continue;
            const float* br = in + c*50176 + iy*224;
            for (int kx = 0; kx < 7; ++kx) {
              int ix = ixb + kx;
              if ((unsigned)ix >= 224u) continue;
              a = fmaf(br[ix], wsm[c*49+ky*7+kx], a);
            }
          }
        }
        acc[j] = a;
      }
      a0 = acc[0]; a1 = acc[1]; a2 = acc[2]; a3 = acc[3];
    }
    ushort4 pk;
    pk.x = f2bf(a0); pk.y = f2bf(a1); pk.z = f2bf(a2); pk.w = f2bf(a3);
    *reinterpret_cast<ushort4*>(op + oy*112 + ox0) = pk;
    lsum += a0+a1+a2+a3;
    lsq  += a0*a0 + a1*a1 + a2*a2 + a3*a3;
  }
  lsum = wred(lsum); lsq = wred(lsq);
  int wid = threadIdx.x >> 6;
  if ((threadIdx.x & 63) == 0) { ssum[wid] = lsum; ssq[wid] = lsq; }
  __syncthreads();
  if (threadIdx.x == 0) {
    atomicAdd(&stats[S1_SUM + oc], ssum[0]+ssum[1]+ssum[2]+ssum[3]);
    atomicAdd(&stats[S1_SQ  + oc], ssq[0]+ssq[1]+ssq[2]+ssq[3]);
  }
}

// ---------------- bn1 + maxpool3 s2 p1 : bf16[64,64,112,112] -> f32[64,64,56,56] ----------------
__global__ void bn_pool1_kernel(const unsigned short* __restrict__ out1,
                                const float* __restrict__ stats,
                                const float* __restrict__ g, const float* __restrict__ bt,
                                float* __restrict__ pool1) {
  int idx = blockIdx.x * 256 + threadIdx.x;
  if (idx >= 12845056) return;
  int x = idx % 56;
  int y = (idx / 56) % 56;
  int bc = idx / 3136;
  int c = bc & 63;
  float mean = stats[S1_SUM + c] * (1.f/802816.f);
  float var  = stats[S1_SQ  + c] * (1.f/802816.f) - mean*mean;
  float scale = g[c] * rsqrtf(var + 1e-5f);
  float shift = bt[c] - mean * scale;
  const unsigned short* src = out1 + (size_t)bc * 12544;
  float m = -3.4e38f;
#pragma unroll
  for (int dy = -1; dy <= 1; ++dy) {
    int iy = 2*y + dy;
    if ((unsigned)iy >= 112u) continue;
#pragma unroll
    for (int dx = -1; dx <= 1; ++dx) {
      int ix = 2*x + dx;
      if ((unsigned)ix >= 112u) continue;
      float v = bf2f(src[iy*112 + ix]);
      m = fmaxf(m, fmaf(v, scale, shift));
    }
  }
  pool1[idx] = m;
}

// ---------------- conv2: [64,56,56] -> [128,28,28], k3 s2 p1, per-sample W ----------------
__global__ __launch_bounds__(256) void conv2_kernel(
    const float* __restrict__ pool1, const float* __restrict__ w2,
    float* __restrict__ out2, float* __restrict__ stats) {
  int oc = blockIdx.x, b = blockIdx.y;
  __shared__ float wsm[576];
  __shared__ float ssum[4], ssq[4];
  const float* wp = w2 + ((size_t)b*128 + oc) * 576;
  for (int i = threadIdx.x; i < 576; i += 256) wsm[i] = wp[i];
  __syncthreads();
  const float* in = pool1 + (size_t)b * 64 * 3136;
  float* op = out2 + ((size_t)b*128 + oc) * 784;
  float lsum = 0.f, lsq = 0.f;
  for (int g = threadIdx.x; g < 392; g += 256) {
    int oy = g / 14;
    int ox0 = (g - oy*14) * 2;
    int iy0 = oy*2 - 1, ix0 = ox0*2 - 1;
    float a0 = 0.f, a1 = 0.f;
    if (oy >= 1 && ox0 >= 1) {
      for (int c = 0; c < 64; ++c) {
        const float* bc = in + c*3136 + iy0*56 + ix0;
#pragma unroll
        for (int ky = 0; ky < 3; ++ky) {
          const float* br = bc + ky*56;
          float r0=br[0], r1=br[1], r2=br[2], r3=br[3], r4=br[4];
          float w0=wsm[c*9+ky*3+0], w1=wsm[c*9+ky*3+1], w2v=wsm[c*9+ky*3+2];
          a0 = fmaf(r0,w0,fmaf(r1,w1,fmaf(r2,w2v,a0)));
          a1 = fmaf(r2,w0,fmaf(r3,w1,fmaf(r4,w2v,a1)));
        }
      }
    } else {
      float acc[2];
#pragma unroll
      for (int j = 0; j < 2; ++j) {
        int ixb = ix0 + 2*j;
        float a = 0.f;
        for (int c = 0; c < 64; ++c) {
          for (int ky = 0; ky < 3; ++ky) {
            int iy = iy0 + ky;
            if ((unsigned)iy >= 56u) continue;
            const float* br = in + c*3136 + iy*56;
            for (int kx = 0; kx < 3; ++kx) {
              int ix = ixb + kx;
              if ((unsigned)ix >= 56u) continue;
              a = fmaf(br[ix], wsm[c*9+ky*3+kx], a);
            }
          }
        }
        acc[j] = a;
      }
      a0 = acc[0]; a1 = acc[1];
    }
    op[oy*28 + ox0    ] = a0;
    op[oy*28 + ox0 + 1] = a1;
    lsum += a0 + a1;
    lsq  += a0*a0 + a1*a1;
  }
  lsum = wred(lsum); lsq = wred(lsq);
  int wid = threadIdx.x >> 6;
  if ((threadIdx.x & 63) == 0) { ssum[wid] = lsum; ssq[wid] = lsq; }
  __syncthreads();
  if (threadIdx.x == 0) {
    atomicAdd(&stats[S2_SUM + oc], ssum[0]+ssum[1]+ssum[2]+ssum[3]);
    atomicAdd(&stats[S2_SQ  + oc], ssq[0]+ssq[1]+ssq[2]+ssq[3]);
  }
}

// ---------------- bn2 + maxpool3 s2 p1 : [64,128,28,28] -> [64,128,14,14] ----------------
__global__ void bn_pool2_kernel(const float* __restrict__ out2,
                                const float* __restrict__ stats,
                                const float* __restrict__ g, const float* __restrict__ bt,
                                float* __restrict__ pool2) {
  int idx = blockIdx.x * 256 + threadIdx.x;
  if (idx >= 1605632) return;
  int x = idx % 14;
  int y = (idx / 14) % 14;
  int bc = idx / 196;
  int c = bc & 127;
  float mean = stats[S2_SUM + c] * (1.f/50176.f);
  float var  = stats[S2_SQ  + c] * (1.f/50176.f) - mean*mean;
  float scale = g[c] * rsqrtf(var + 1e-5f);
  float shift = bt[c] - mean * scale;
  const float* src = out2 + (size_t)bc * 784;
  float m = -3.4e38f;
#pragma unroll
  for (int dy = -1; dy <= 1; ++dy) {
    int iy = 2*y + dy;
    if ((unsigned)iy >= 28u) continue;
#pragma unroll
    for (int dx = -1; dx <= 1; ++dx) {
      int ix = 2*x + dx;
      if ((unsigned)ix >= 28u) continue;
      m = fmaxf(m, fmaf(src[iy*28 + ix], scale, shift));
    }
  }
  pool2[idx] = m;
}

// ---------------- residual convs ----------------
// conv 3x3 s2 p1: [128,14,14] -> [256,7,7], shared W
__global__ __launch_bounds__(64) void res_conv1_kernel(
    const float* __restrict__ pool2, const float* __restrict__ w,
    float* __restrict__ outp, float* __restrict__ stats) {
  int oc = blockIdx.x, b = blockIdx.y;
  __shared__ float wsm[1152];
  const float* wp = w + (size_t)oc * 1152;
  for (int i = threadIdx.x; i < 1152; i += 64) wsm[i] = wp[i];
  __syncthreads();
  const float* in = pool2 + (size_t)b * 128 * 196;
  int lane = threadIdx.x;
  float val = 0.f;
  if (lane < 49) {
    int oy = lane / 7, ox = lane - oy*7;
    int iy0 = 2*oy - 1, ix0 = 2*ox - 1;
    float acc = 0.f;
    for (int c = 0; c < 128; ++c) {
      const float* bc = in + c*196;
#pragma unroll
      for (int ky = 0; ky < 3; ++ky) {
        int iy = iy0 + ky;
        if ((unsigned)iy >= 14u) continue;
        const float* br = bc + iy*14;
#pragma unroll
        for (int kx = 0; kx < 3; ++kx) {
          int ix = ix0 + kx;
          if ((unsigned)ix >= 14u) continue;
          acc = fmaf(br[ix], wsm[c*9 + ky*3 + kx], acc);
        }
      }
    }
    outp[((size_t)b*256 + oc)*49 + lane] = acc;
    val = acc;
  }
  float s = wred(val);
  float q = wred(val*val);
  if (lane == 0) { atomicAdd(&stats[R1_SUM + oc], s); atomicAdd(&stats[R1_SQ + oc], q); }
}

// conv 3x3 s1 p1: [256,7,7] -> [256,7,7], shared W
__global__ __launch_bounds__(64) void res_conv2_kernel(
    const float* __restrict__ l1, const float* __restrict__ w,
    float* __restrict__ outp, float* __restrict__ stats) {
  int oc = blockIdx.x, b = blockIdx.y;
  __shared__ float wsm[2304];
  const float* wp = w + (size_t)oc * 2304;
  for (int i = threadIdx.x; i < 2304; i += 64) wsm[i] = wp[i];
  __syncthreads();
  const float* in = l1 + (size_t)b * 256 * 49;
  int lane = threadIdx.x;
  float val = 0.f;
  if (lane < 49) {
    int oy = lane / 7, ox = lane - oy*7;
    float acc = 0.f;
    for (int c = 0; c < 256; ++c) {
      const float* bc = in + c*49;
#pragma unroll
      for (int ky = 0; ky < 3; ++ky) {
        int iy = oy + ky - 1;
        if ((unsigned)iy >= 7u) continue;
        const float* br = bc + iy*7;
#pragma unroll
        for (int kx = 0; kx < 3; ++kx) {
          int ix = ox + kx - 1;
          if ((unsigned)ix >= 7u) continue;
          acc = fmaf(br[ix], wsm[c*9 + ky*3 + kx], acc);
        }
      }
    }
    outp[((size_t)b*256 + oc)*49 + lane] = acc;
    val = acc;
  }
  float s = wred(val);
  float q = wred(val*val);
  if (lane == 0) { atomicAdd(&stats[R2_SUM + oc], s); atomicAdd(&stats[R2_SQ + oc], q); }
}

// conv 1x1 s2: [128,14,14] -> [256,7,7]
__global__ __launch_bounds__(64) void res_short_kernel(
    const float* __restrict__ pool2, const float* __restrict__ w,
    float* __restrict__ outp, float* __restrict__ stats) {
  int oc = blockIdx.x, b = blockIdx.y;
  __shared__ float wsm[128];
  if (threadIdx.x < 64) {
    wsm[threadIdx.x]      = w[(size_t)oc*128 + threadIdx.x];
    wsm[threadIdx.x + 64] = w[(size_t)oc*128 + 64 + threadIdx.x];
  }
  __syncthreads();
  int lane = threadIdx.x;
  float val = 0.f;
  if (lane < 49) {
    int oy = lane / 7, ox = lane - oy*7;
    const float* in = pool2 + (size_t)b * 128 * 196 + oy*28 + ox*2;
    float acc = 0.f;
    for (int c = 0; c < 128; ++c) acc = fmaf(in[c*196], wsm[c], acc);
    outp[((size_t)b*256 + oc)*49 + lane] = acc;
    val = acc;
  }
  float s = wred(val);
  float q = wred(val*val);
  if (lane == 0) { atomicAdd(&stats[RS_SUM + oc], s); atomicAdd(&stats[RS_SQ + oc], q); }
}

// l1 = relu(bn(l1pre))
__global__ void bn_relu_kernel(const float* __restrict__ src, const float* __restrict__ stats,
                               const float* __restrict__ g, const float* __restrict__ bt,
                               float* __restrict__ dst) {
  int idx = blockIdx.x * 256 + threadIdx.x;
  if (idx >= 802816) return;
  int c = (idx / 49) & 255;
  float mean = stats[R1_SUM + c] * (1.f/3136.f);
  float var  = stats[R1_SQ  + c] * (1.f/3136.f) - mean*mean;
  float scale = g[c] * rsqrtf(var + 1e-5f);
  float shift = bt[c] - mean*scale;
  float v = fmaf(src[idx], scale, shift);
  dst[idx] = v > 0.f ? v : 0.f;
}

// res = relu(bn2(l2pre) + bns(rpre))
__global__ void res_merge_kernel(const float* __restrict__ l2pre, const float* __restrict__ rpre,
                                 const float* __restrict__ stats,
                                 const float* __restrict__ g2, const float* __restrict__ b2,
                                 const float* __restrict__ gs, const float* __restrict__ bs,
                                 float* __restrict__ dst) {
  int idx = blockIdx.x * 256 + threadIdx.x;
  if (idx >= 802816) return;
  int c = (idx / 49) & 255;
  float m2 = stats[R2_SUM + c] * (1.f/3136.f);
  float v2 = stats[R2_SQ  + c] * (1.f/3136.f) - m2*m2;
  float s2 = g2[c] * rsqrtf(v2 + 1e-5f);
  float h2 = b2[c] - m2*s2;
  float ms = stats[RS_SUM + c] * (1.f/3136.f);
  float vs = stats[RS_SQ  + c] * (1.f/3136.f) - ms*ms;
  float ss = gs[c] * rsqrtf(vs + 1e-5f);
  float hs = bs[c] - ms*ss;
  float v = fmaf(l2pre[idx], s2, h2) + fmaf(rpre[idx], ss, hs);
  dst[idx] = v > 0.f ? v : 0.f;
}

// xbar[b,c] = mean over 49
__global__ void xbar_kernel(const float* __restrict__ res, float* __restrict__ xbar) {
  int b = blockIdx.x, c = threadIdx.x;
  const float* src = res + ((size_t)b*256 + c) * 49;
  float s = 0.f;
  for (int i = 0; i < 49; ++i) s += src[i];
  xbar[b*256 + c] = s * (1.f/49.f);
}

// u[b,e] = sum_c wv[e,c] * xbar[b,c]
__global__ void u_kernel(const float* __restrict__ wv, const float* __restrict__ xbar,
                         float* __restrict__ u) {
  int b = blockIdx.y;
  int e = blockIdx.x * 256 + threadIdx.x;
  __shared__ float xs[256];
  xs[threadIdx.x] = xbar[b*256 + threadIdx.x];
  __syncthreads();
  const float* wr = wv + (size_t)e * 256;
  float s = 0.f;
  for (int c = 0; c < 256; ++c) s = fmaf(wr[c], xs[c], s);
  u[b*1024 + e] = s;
}

// z = wo@u + bo ; out = fc_w@z + fc_b
__global__ void head_kernel(const float* __restrict__ wo, const float* __restrict__ bo,
                            const float* __restrict__ u, const float* __restrict__ fcw,
                            const float* __restrict__ fcb, float* __restrict__ out) {
  int b = blockIdx.x, t = threadIdx.x;
  __shared__ float us[1024];
  __shared__ float zs[256];
  for (int i = t; i < 1024; i += 256) us[i] = u[b*1024 + i];
  __syncthreads();
  float z = bo[t];
  const float* wr = wo + (size_t)t * 1024;
  for (int e = 0; e < 1024; ++e) z = fmaf(wr[e], us[e], z);
  zs[t] = z;
  __syncthreads();
  if (t < 50) {
    float s = fcb[t];
    const float* fr = fcw + t*256;
    for (int o = 0; o < 256; ++o) s = fmaf(fr[o], zs[o], s);
    out[b*50 + t] = s;
  }
}

// ---------------- launch ----------------
extern "C" void kernel_launch(void* const* d_in, const int* in_sizes, int n_in,
                              void* d_out, int out_size, void* d_ws, size_t ws_size,
                              hipStream_t stream) {
  const float* imgs = (const float*)d_in[0];
  const float* a1f1 = (const float*)d_in[1];
  const float* a1f2 = (const float*)d_in[2];
  const float* a1b  = (const float*)d_in[3];
  const float* dy1  = (const float*)d_in[4];
  const float* bn1g = (const float*)d_in[5];
  const float* bn1b = (const float*)d_in[6];
  const float* a2f1 = (const float*)d_in[7];
  const float* a2f2 = (const float*)d_in[8];
  const float* a2b  = (const float*)d_in[9];
  const float* dy2  = (const float*)d_in[10];
  const float* bn2g = (const float*)d_in[11];
  const float* bn2b = (const float*)d_in[12];
  const float* rc1w = (const float*)d_in[13];
  const float* rb1g = (const float*)d_in[14];
  const float* rb1b = (const float*)d_in[15];
  const float* rc2w = (const float*)d_in[16];
  const float* rb2g = (const float*)d_in[17];
  const float* rb2b = (const float*)d_in[18];
  const float* rsw  = (const float*)d_in[19];
  const float* rbsg = (const float*)d_in[20];
  const float* rbsb = (const float*)d_in[21];
  // d_in[22]=wq, d_in[23]=wk are mathematically unused (softmax row-sums to 1)
  const float* wv_  = (const float*)d_in[24];
  const float* wo_  = (const float*)d_in[25];
  const float* bo_  = (const float*)d_in[26];
  const float* fcw  = (const float*)d_in[27];
  const float* fcb  = (const float*)d_in[28];
  float* out = (float*)d_out;

  char* ws = (char*)d_ws;
  unsigned short* out1 = (unsigned short*)(ws + OFF_OUT1);
  float* out2  = (float*)(ws + OFF_OUT2);
  float* pool1 = (float*)(ws + OFF_POOL1);
  float* pool2 = (float*)(ws + OFF_POOL2);
  float* w1    = (float*)(ws + OFF_W1);
  float* w2    = (float*)(ws + OFF_W2);
  float* l1pre = (float*)(ws + OFF_L1PRE);
  float* l1    = (float*)(ws + OFF_L1);
  float* l2pre = (float*)(ws + OFF_L2PRE);
  float* rpre  = (float*)(ws + OFF_RPRE);
  float* res   = (float*)(ws + OFF_RES);
  float* stats = (float*)(ws + OFF_STATS);
  float* attn1 = (float*)(ws + OFF_ATTN1);
  float* attn2 = (float*)(ws + OFF_ATTN2);
  float* xbar  = (float*)(ws + OFF_XBAR);
  float* u     = (float*)(ws + OFF_U);

  hipMemsetAsync(stats, 0, STATS_N * sizeof(float), stream);

  attn1_kernel<<<64, 256, 0, stream>>>(imgs, a1f1, a1f2, a1b, attn1);
  agg_w_kernel<<<dim3(37, 64), 256, 0, stream>>>(attn1, dy1, w1, 9408);
  conv1_kernel<<<dim3(64, 64), 256, 0, stream>>>(imgs, w1, out1, stats);
  bn_pool1_kernel<<<50176, 256, 0, stream>>>(out1, stats, bn1g, bn1b, pool1);

  attn2_kernel<<<64, 256, 0, stream>>>(pool1, a2f1, a2f2, a2b, attn2);
  agg_w_kernel<<<dim3(288, 64), 256, 0, stream>>>(attn2, dy2, w2, 73728);
  conv2_kernel<<<dim3(128, 64), 256, 0, stream>>>(pool1, w2, out2, stats);
  bn_pool2_kernel<<<6272, 256, 0, stream>>>(out2, stats, bn2g, bn2b, pool2);

  res_conv1_kernel<<<dim3(256, 64), 64, 0, stream>>>(pool2, rc1w, l1pre, stats);
  bn_relu_kernel<<<3136, 256, 0, stream>>>(l1pre, stats, rb1g, rb1b, l1);
  res_conv2_kernel<<<dim3(256, 64), 64, 0, stream>>>(l1, rc2w, l2pre, stats);
  res_short_kernel<<<dim3(256, 64), 64, 0, stream>>>(pool2, rsw, rpre, stats);
  res_merge_kernel<<<3136, 256, 0, stream>>>(l2pre, rpre, stats, rb2g, rb2b, rbsg, rbsb, res);

  xbar_kernel<<<64, 256, 0, stream>>>(res, xbar);
  u_kernel<<<dim3(4, 64), 256, 0, stream>>>(wv_, xbar, u);
  head_kernel<<<64, 256, 0, stream>>>(wo_, bo_, u, fcw, fcb, out);
}

// Round 2
// 2539.541 us; speedup vs baseline: 6.0044x; 6.0044x over previous
//
#include <hip/hip_runtime.h>
#include <hip/hip_bf16.h>

#define DEV static __device__ __forceinline__

// ---------------- helpers ----------------
DEV float wred(float v) {
#pragma unroll
  for (int off = 32; off > 0; off >>= 1) v += __shfl_down(v, off, 64);
  return v;
}

DEV unsigned short f2bf(float f) {
  union { float f; unsigned u; } a; a.f = f;
  unsigned u = a.u;
  unsigned lsb = (u >> 16) & 1u;
  u += 0x7fffu + lsb;            // round-to-nearest-even
  return (unsigned short)(u >> 16);
}
DEV float bf2f(unsigned short us) {
  union { unsigned u; float f; } a; a.u = ((unsigned)us) << 16;
  return a.f;
}

// ---------------- ws layout (bytes) ----------------
#define OFF_OUT1   ((size_t)0)           // bf16 [64,64,112,112]
#define OFF_OUT2   ((size_t)0)           // f32  [64,128,28,28]  (reuses OUT1 after pool1)
#define OFF_POOL2  ((size_t)25690112)    // f32  [64,128,14,14]
#define OFF_W2     ((size_t)32112640)    // f32  [64,128,64,3,3]
#define OFF_L1PRE  ((size_t)50987008)    // f32  [64,256,7,7]
#define OFF_L1     ((size_t)54198272)
#define OFF_L2PRE  ((size_t)57409536)
#define OFF_RPRE   ((size_t)60620800)
#define OFF_RES    ((size_t)63832064)
#define OFF_POOL1  ((size_t)102760448)   // f32  [64,64,56,56]
#define OFF_W1     ((size_t)154140672)   // f32  [64,64,3,7,7]
#define OFF_STATS  ((size_t)156549120)   // 1920 f32
#define OFF_ATTN1  (OFF_STATS + 8192)
#define OFF_ATTN2  (OFF_ATTN1 + 2048)
#define OFF_XBAR   (OFF_ATTN2 + 2048)    // [64,256] f32
#define OFF_U      (OFF_XBAR + 65536)    // [64,1024] f32

#define S1_SUM 0
#define S1_SQ  64
#define S2_SUM 128
#define S2_SQ  256
#define R1_SUM 384
#define R1_SQ  640
#define R2_SUM 896
#define R2_SQ  1152
#define RS_SUM 1408
#define RS_SQ  1664
#define STATS_N 1920

// ---------------- attention MLPs ----------------
__global__ void attn1_kernel(const float* __restrict__ imgs,
                             const float* __restrict__ fc1w,   // [8,3]
                             const float* __restrict__ fc2w,   // [8,8]
                             const float* __restrict__ fc2b,   // [8]
                             float* __restrict__ attn) {       // [64,8]
  int b = blockIdx.x, tid = threadIdx.x, wid = tid >> 6, lane = tid & 63;
  __shared__ float pooled[3];
  const float* x = imgs + (size_t)b * 150528;
  if (wid < 3) {
    const float4* src = (const float4*)(x + wid * 50176);   // 12544 float4
    float s = 0.f;
    for (int i = lane; i < 12544; i += 64) {
      float4 v = src[i];
      s += v.x + v.y + v.z + v.w;
    }
    s = wred(s);
    if (lane == 0) pooled[wid] = s * (1.f / 50176.f);
  }
  __syncthreads();
  if (tid == 0) {
    float h[8];
#pragma unroll
    for (int j = 0; j < 8; ++j) {
      float a = fc1w[j*3+0]*pooled[0] + fc1w[j*3+1]*pooled[1] + fc1w[j*3+2]*pooled[2];
      h[j] = a > 0.f ? a : 0.f;
    }
    float lg[8], mx = -1e30f;
#pragma unroll
    for (int k = 0; k < 8; ++k) {
      float a = fc2b[k];
#pragma unroll
      for (int j = 0; j < 8; ++j) a = fmaf(fc2w[k*8+j], h[j], a);
      lg[k] = a; mx = fmaxf(mx, a);
    }
    float den = 0.f;
#pragma unroll
    for (int k = 0; k < 8; ++k) { lg[k] = expf(lg[k]-mx); den += lg[k]; }
    float inv = 1.f/den;
#pragma unroll
    for (int k = 0; k < 8; ++k) attn[b*8+k] = lg[k]*inv;
  }
}

__global__ void attn2_kernel(const float* __restrict__ pool1,
                             const float* __restrict__ fc1w,   // [17,64]
                             const float* __restrict__ fc2w,   // [8,17]
                             const float* __restrict__ fc2b,   // [8]
                             float* __restrict__ attn) {       // [64,8]
  int b = blockIdx.x, tid = threadIdx.x, wid = tid >> 6, lane = tid & 63;
  __shared__ float pooled[64];
  const float* x = pool1 + (size_t)b * 64 * 3136;
  for (int c = wid; c < 64; c += 4) {
    const float4* src = (const float4*)(x + (size_t)c * 3136);  // 784 float4
    float s = 0.f;
    for (int i = lane; i < 784; i += 64) {
      float4 v = src[i];
      s += v.x + v.y + v.z + v.w;
    }
    s = wred(s);
    if (lane == 0) pooled[c] = s * (1.f/3136.f);
  }
  __syncthreads();
  if (tid == 0) {
    float h[17];
    for (int j = 0; j < 17; ++j) {
      float a = 0.f;
      for (int c = 0; c < 64; ++c) a = fmaf(fc1w[j*64+c], pooled[c], a);
      h[j] = a > 0.f ? a : 0.f;
    }
    float lg[8], mx = -1e30f;
    for (int k = 0; k < 8; ++k) {
      float a = fc2b[k];
      for (int j = 0; j < 17; ++j) a = fmaf(fc2w[k*17+j], h[j], a);
      lg[k] = a; mx = fmaxf(mx, a);
    }
    float den = 0.f;
    for (int k = 0; k < 8; ++k) { lg[k] = expf(lg[k]-mx); den += lg[k]; }
    float inv = 1.f/den;
    for (int k = 0; k < 8; ++k) attn[b*8+k] = lg[k]*inv;
  }
}

// w[b,i] = sum_k attn[b,k] * dyw[k,i]
__global__ void agg_w_kernel(const float* __restrict__ attn, const float* __restrict__ dyw,
                             float* __restrict__ w, int per) {
  int b = blockIdx.y;
  int i = blockIdx.x * 256 + threadIdx.x;
  if (i >= per) return;
  float s = 0.f;
#pragma unroll
  for (int k = 0; k < 8; ++k) s = fmaf(attn[b*8+k], dyw[(size_t)k*per + i], s);
  w[(size_t)b*per + i] = s;
}

// ---------------- conv1: [3,224,224] -> [64,112,112], k7 s2 p3, per-sample W ----------------
// Block = (row-tile of 4 out rows, sample b). All 64 oc per block.
// thread: pxg=t&15 owns 7 px (ox=7*pxg..+6), ocg=t>>4 owns 4 oc. 2 passes of 2 rows.
// weights in LDS [k][oc] xor-swizzled (oc' = (oc+4k)&63) so staging writes avoid 32-way
// conflicts while compute reads stay contiguous float4 broadcasts.
__global__ __launch_bounds__(256) void conv1_kernel(
    const float* __restrict__ imgs, const float* __restrict__ w1,
    unsigned short* __restrict__ out1, float* __restrict__ stats) {
  int tile = blockIdx.x, b = blockIdx.y;
  int t = threadIdx.x, pxg = t & 15, ocg4 = (t >> 4) * 4;
  __shared__ float wlds[9408];   // 147 k x 64 oc (swizzled)
  __shared__ float ilds[2088];   // 9 rows x 232 (224 + 3 zero-pad each side, +1)
  const float* wp = w1 + (size_t)b * 9408;
  for (int i = t; i < 9408; i += 256) {
    int oc = i / 147, k = i - oc * 147;
    wlds[(k << 6) + ((oc + 4 * k) & 63)] = wp[i];
  }
  const float* img = imgs + (size_t)b * 150528;
  float lsum[4] = {0.f,0.f,0.f,0.f}, lsq[4] = {0.f,0.f,0.f,0.f};
#pragma unroll 1
  for (int oy2 = 0; oy2 < 2; ++oy2) {
    float acc[2][7][4];
#pragma unroll
    for (int ol = 0; ol < 2; ++ol)
#pragma unroll
      for (int j = 0; j < 7; ++j)
#pragma unroll
        for (int q = 0; q < 4; ++q) acc[ol][j][q] = 0.f;
    int iyb = tile * 8 + oy2 * 4 - 3;
#pragma unroll 1
    for (int c = 0; c < 3; ++c) {
      __syncthreads();
      for (int i = t; i < 2088; i += 256) {
        int r = i / 232, p = i - r * 232;
        int iy = iyb + r, x = p - 3;
        float v = 0.f;
        if ((unsigned)iy < 224u && (unsigned)x < 224u) v = img[c * 50176 + iy * 224 + x];
        ilds[i] = v;
      }
      __syncthreads();
#pragma unroll 1
      for (int ky = 0; ky < 7; ++ky) {
        float rA[20], rB[20];
        const float2* pA = (const float2*)&ilds[ky * 232 + 14 * pxg];
        const float2* pB = (const float2*)&ilds[(ky + 2) * 232 + 14 * pxg];
#pragma unroll
        for (int m = 0; m < 10; ++m) {
          float2 v = pA[m]; rA[2*m] = v.x; rA[2*m+1] = v.y;
          float2 u = pB[m]; rB[2*m] = u.x; rB[2*m+1] = u.y;
        }
#pragma unroll
        for (int kx = 0; kx < 7; ++kx) {
          int k = c * 49 + ky * 7 + kx;
          const float4 w = *(const float4*)&wlds[(k << 6) + ((ocg4 + 4 * k) & 63)];
#pragma unroll
          for (int j = 0; j < 7; ++j) {
            float a = rA[2*j + kx], bb = rB[2*j + kx];
            acc[0][j][0] = fmaf(a, w.x, acc[0][j][0]);
            acc[0][j][1] = fmaf(a, w.y, acc[0][j][1]);
            acc[0][j][2] = fmaf(a, w.z, acc[0][j][2]);
            acc[0][j][3] = fmaf(a, w.w, acc[0][j][3]);
            acc[1][j][0] = fmaf(bb, w.x, acc[1][j][0]);
            acc[1][j][1] = fmaf(bb, w.y, acc[1][j][1]);
            acc[1][j][2] = fmaf(bb, w.z, acc[1][j][2]);
            acc[1][j][3] = fmaf(bb, w.w, acc[1][j][3]);
          }
        }
      }
    }
    int oy0 = tile * 4 + oy2 * 2, ox0 = pxg * 7;
#pragma unroll
    for (int ol = 0; ol < 2; ++ol) {
      unsigned short* op = out1 + ((size_t)b * 64 + ocg4) * 12544 + (oy0 + ol) * 112 + ox0;
#pragma unroll
      for (int q = 0; q < 4; ++q) {
#pragma unroll
        for (int j = 0; j < 7; ++j) {
          float v = acc[ol][j][q];
          op[q * 12544 + j] = f2bf(v);
          lsum[q] += v; lsq[q] += v * v;
        }
      }
    }
  }
  // reduce across the 16 lanes sharing each oc group (consecutive lanes)
#pragma unroll
  for (int q = 0; q < 4; ++q) {
#pragma unroll
    for (int off = 1; off < 16; off <<= 1) {
      lsum[q] += __shfl_xor(lsum[q], off, 64);
      lsq[q]  += __shfl_xor(lsq[q],  off, 64);
    }
  }
  if ((t & 15) == 0) {
#pragma unroll
    for (int q = 0; q < 4; ++q) {
      atomicAdd(&stats[S1_SUM + ocg4 + q], lsum[q]);
      atomicAdd(&stats[S1_SQ  + ocg4 + q], lsq[q]);
    }
  }
}

// ---------------- bn1 + maxpool3 s2 p1 ----------------
__global__ void bn_pool1_kernel(const unsigned short* __restrict__ out1,
                                const float* __restrict__ stats,
                                const float* __restrict__ g, const float* __restrict__ bt,
                                float* __restrict__ pool1) {
  int idx = blockIdx.x * 256 + threadIdx.x;
  if (idx >= 12845056) return;
  int x = idx % 56;
  int y = (idx / 56) % 56;
  int bc = idx / 3136;
  int c = bc & 63;
  float mean = stats[S1_SUM + c] * (1.f/802816.f);
  float var  = stats[S1_SQ  + c] * (1.f/802816.f) - mean*mean;
  float scale = g[c] * rsqrtf(var + 1e-5f);
  float shift = bt[c] - mean * scale;
  const unsigned short* src = out1 + (size_t)bc * 12544;
  float m = -3.4e38f;
#pragma unroll
  for (int dy = -1; dy <= 1; ++dy) {
    int iy = 2*y + dy;
    if ((unsigned)iy >= 112u) continue;
#pragma unroll
    for (int dx = -1; dx <= 1; ++dx) {
      int ix = 2*x + dx;
      if ((unsigned)ix >= 112u) continue;
      float v = bf2f(src[iy*112 + ix]);
      m = fmaxf(m, fmaf(v, scale, shift));
    }
  }
  pool1[idx] = m;
}

// ---------------- conv2: [64,56,56] -> [128,28,28], k3 s2 p1, per-sample W ----------------
// Block = (oc-half(64) x 4-row tile, sample). thread: pxg=t&15 -> (row rr=pxg>>2, 7 px),
// ocg -> 4 oc. 8 input-channel chunks staged through LDS.
__global__ __launch_bounds__(256) void conv2_kernel(
    const float* __restrict__ pool1, const float* __restrict__ w2,
    float* __restrict__ out2, float* __restrict__ stats) {
  int bx = blockIdx.x, b = blockIdx.y;
  int och = bx & 1, T = bx >> 1;
  int t = threadIdx.x, pxg = t & 15, ocg4 = (t >> 4) * 4;
  int rr = pxg >> 2, cx = pxg & 3;
  __shared__ float wl[4608];   // 72 k x 64 oc (swizzled)
  __shared__ float il[4176];   // 8 ch x 9 rows x 58 (56 + 1 pad each side)
  const float* in = pool1 + (size_t)b * 200704;
  const float* wp = w2 + ((size_t)b * 128 + och * 64) * 576;
  float acc[7][4];
#pragma unroll
  for (int j = 0; j < 7; ++j)
#pragma unroll
    for (int q = 0; q < 4; ++q) acc[j][q] = 0.f;
  int iyb = T * 8 - 1;
#pragma unroll 1
  for (int chunk = 0; chunk < 8; ++chunk) {
    __syncthreads();
    int c0 = chunk * 8;
    for (int i = t; i < 4608; i += 256) {
      int oc = i / 72, kc = i - oc * 72;
      wl[kc * 64 + ((oc + 4 * kc) & 63)] = wp[oc * 576 + c0 * 9 + kc];
    }
    for (int i = t; i < 4176; i += 256) {
      int cc = i / 522, rem = i - cc * 522, r = rem / 58, p = rem - r * 58;
      int iy = iyb + r, x = p - 1;
      float v = 0.f;
      if ((unsigned)iy < 56u && (unsigned)x < 56u) v = in[(c0 + cc) * 3136 + iy * 56 + x];
      il[i] = v;
    }
    __syncthreads();
#pragma unroll 1
    for (int cc = 0; cc < 8; ++cc) {
#pragma unroll
      for (int ky = 0; ky < 3; ++ky) {
        int r = 2 * rr + ky;
        float rA[16];
        const float2* pA = (const float2*)&il[(cc * 9 + r) * 58 + 14 * cx];
#pragma unroll
        for (int m = 0; m < 8; ++m) { float2 v = pA[m]; rA[2*m] = v.x; rA[2*m+1] = v.y; }
#pragma unroll
        for (int kx = 0; kx < 3; ++kx) {
          int kc = cc * 9 + ky * 3 + kx;
          const float4 w = *(const float4*)&wl[(kc << 6) + ((ocg4 + 4 * kc) & 63)];
#pragma unroll
          for (int j = 0; j < 7; ++j) {
            float a = rA[2*j + kx];
            acc[j][0] = fmaf(a, w.x, acc[j][0]);
            acc[j][1] = fmaf(a, w.y, acc[j][1]);
            acc[j][2] = fmaf(a, w.z, acc[j][2]);
            acc[j][3] = fmaf(a, w.w, acc[j][3]);
          }
        }
      }
    }
  }
  int oy = T * 4 + rr, ox0 = cx * 7;
  int ocb = och * 64 + ocg4;
  float* op = out2 + ((size_t)b * 128 + ocb) * 784 + oy * 28 + ox0;
  float ls[4] = {0.f,0.f,0.f,0.f}, lq[4] = {0.f,0.f,0.f,0.f};
#pragma unroll
  for (int q = 0; q < 4; ++q) {
#pragma unroll
    for (int j = 0; j < 7; ++j) {
      float v = acc[j][q];
      op[q * 784 + j] = v;
      ls[q] += v; lq[q] += v * v;
    }
  }
#pragma unroll
  for (int q = 0; q < 4; ++q) {
#pragma unroll
    for (int off = 1; off < 16; off <<= 1) {
      ls[q] += __shfl_xor(ls[q], off, 64);
      lq[q] += __shfl_xor(lq[q], off, 64);
    }
  }
  if ((t & 15) == 0) {
#pragma unroll
    for (int q = 0; q < 4; ++q) {
      atomicAdd(&stats[S2_SUM + ocb + q], ls[q]);
      atomicAdd(&stats[S2_SQ  + ocb + q], lq[q]);
    }
  }
}

// ---------------- bn2 + maxpool3 s2 p1 ----------------
__global__ void bn_pool2_kernel(const float* __restrict__ out2,
                                const float* __restrict__ stats,
                                const float* __restrict__ g, const float* __restrict__ bt,
                                float* __restrict__ pool2) {
  int idx = blockIdx.x * 256 + threadIdx.x;
  if (idx >= 1605632) return;
  int x = idx % 14;
  int y = (idx / 14) % 14;
  int bc = idx / 196;
  int c = bc & 127;
  float mean = stats[S2_SUM + c] * (1.f/50176.f);
  float var  = stats[S2_SQ  + c] * (1.f/50176.f) - mean*mean;
  float scale = g[c] * rsqrtf(var + 1e-5f);
  float shift = bt[c] - mean * scale;
  const float* src = out2 + (size_t)bc * 784;
  float m = -3.4e38f;
#pragma unroll
  for (int dy = -1; dy <= 1; ++dy) {
    int iy = 2*y + dy;
    if ((unsigned)iy >= 28u) continue;
#pragma unroll
    for (int dx = -1; dx <= 1; ++dx) {
      int ix = 2*x + dx;
      if ((unsigned)ix >= 28u) continue;
      m = fmaxf(m, fmaf(src[iy*28 + ix], scale, shift));
    }
  }
  pool2[idx] = m;
}

// ---------------- residual convs ----------------
__global__ __launch_bounds__(64) void res_conv1_kernel(
    const float* __restrict__ pool2, const float* __restrict__ w,
    float* __restrict__ outp, float* __restrict__ stats) {
  int oc = blockIdx.x, b = blockIdx.y;
  __shared__ float wsm[1152];
  const float* wp = w + (size_t)oc * 1152;
  for (int i = threadIdx.x; i < 1152; i += 64) wsm[i] = wp[i];
  __syncthreads();
  const float* in = pool2 + (size_t)b * 128 * 196;
  int lane = threadIdx.x;
  float val = 0.f;
  if (lane < 49) {
    int oy = lane / 7, ox = lane - oy*7;
    int iy0 = 2*oy - 1, ix0 = 2*ox - 1;
    float acc = 0.f;
    for (int c = 0; c < 128; ++c) {
      const float* bc = in + c*196;
#pragma unroll
      for (int ky = 0; ky < 3; ++ky) {
        int iy = iy0 + ky;
        if ((unsigned)iy >= 14u) continue;
        const float* br = bc + iy*14;
#pragma unroll
        for (int kx = 0; kx < 3; ++kx) {
          int ix = ix0 + kx;
          if ((unsigned)ix >= 14u) continue;
          acc = fmaf(br[ix], wsm[c*9 + ky*3 + kx], acc);
        }
      }
    }
    outp[((size_t)b*256 + oc)*49 + lane] = acc;
    val = acc;
  }
  float s = wred(val);
  float q = wred(val*val);
  if (lane == 0) { atomicAdd(&stats[R1_SUM + oc], s); atomicAdd(&stats[R1_SQ + oc], q); }
}

__global__ __launch_bounds__(64) void res_conv2_kernel(
    const float* __restrict__ l1, const float* __restrict__ w,
    float* __restrict__ outp, float* __restrict__ stats) {
  int oc = blockIdx.x, b = blockIdx.y;
  __shared__ float wsm[2304];
  const float* wp = w + (size_t)oc * 2304;
  for (int i = threadIdx.x; i < 2304; i += 64) wsm[i] = wp[i];
  __syncthreads();
  const float* in = l1 + (size_t)b * 256 * 49;
  int lane = threadIdx.x;
  float val = 0.f;
  if (lane < 49) {
    int oy = lane / 7, ox = lane - oy*7;
    float acc = 0.f;
    for (int c = 0; c < 256; ++c) {
      const float* bc = in + c*49;
#pragma unroll
      for (int ky = 0; ky < 3; ++ky) {
        int iy = oy + ky - 1;
        if ((unsigned)iy >= 7u) continue;
        const float* br = bc + iy*7;
#pragma unroll
        for (int kx = 0; kx < 3; ++kx) {
          int ix = ox + kx - 1;
          if ((unsigned)ix >= 7u) continue;
          acc = fmaf(br[ix], wsm[c*9 + ky*3 + kx], acc);
        }
      }
    }
    outp[((size_t)b*256 + oc)*49 + lane] = acc;
    val = acc;
  }
  float s = wred(val);
  float q = wred(val*val);
  if (lane == 0) { atomicAdd(&stats[R2_SUM + oc], s); atomicAdd(&stats[R2_SQ + oc], q); }
}

__global__ __launch_bounds__(64) void res_short_kernel(
    const float* __restrict__ pool2, const float* __restrict__ w,
    float* __restrict__ outp, float* __restrict__ stats) {
  int oc = blockIdx.x, b = blockIdx.y;
  __shared__ float wsm[128];
  if (threadIdx.x < 64) {
    wsm[threadIdx.x]      = w[(size_t)oc*128 + threadIdx.x];
    wsm[threadIdx.x + 64] = w[(size_t)oc*128 + 64 + threadIdx.x];
  }
  __syncthreads();
  int lane = threadIdx.x;
  float val = 0.f;
  if (lane < 49) {
    int oy = lane / 7, ox = lane - oy*7;
    const float* in = pool2 + (size_t)b * 128 * 196 + oy*28 + ox*2;
    float acc = 0.f;
    for (int c = 0; c < 128; ++c) acc = fmaf(in[c*196], wsm[c], acc);
    outp[((size_t)b*256 + oc)*49 + lane] = acc;
    val = acc;
  }
  float s = wred(val);
  float q = wred(val*val);
  if (lane == 0) { atomicAdd(&stats[RS_SUM + oc], s); atomicAdd(&stats[RS_SQ + oc], q); }
}

__global__ void bn_relu_kernel(const float* __restrict__ src, const float* __restrict__ stats,
                               const float* __restrict__ g, const float* __restrict__ bt,
                               float* __restrict__ dst) {
  int idx = blockIdx.x * 256 + threadIdx.x;
  if (idx >= 802816) return;
  int c = (idx / 49) & 255;
  float mean = stats[R1_SUM + c] * (1.f/3136.f);
  float var  = stats[R1_SQ  + c] * (1.f/3136.f) - mean*mean;
  float scale = g[c] * rsqrtf(var + 1e-5f);
  float shift = bt[c] - mean*scale;
  float v = fmaf(src[idx], scale, shift);
  dst[idx] = v > 0.f ? v : 0.f;
}

__global__ void res_merge_kernel(const float* __restrict__ l2pre, const float* __restrict__ rpre,
                                 const float* __restrict__ stats,
                                 const float* __restrict__ g2, const float* __restrict__ b2,
                                 const float* __restrict__ gs, const float* __restrict__ bs,
                                 float* __restrict__ dst) {
  int idx = blockIdx.x * 256 + threadIdx.x;
  if (idx >= 802816) return;
  int c = (idx / 49) & 255;
  float m2 = stats[R2_SUM + c] * (1.f/3136.f);
  float v2 = stats[R2_SQ  + c] * (1.f/3136.f) - m2*m2;
  float s2 = g2[c] * rsqrtf(v2 + 1e-5f);
  float h2 = b2[c] - m2*s2;
  float ms = stats[RS_SUM + c] * (1.f/3136.f);
  float vs = stats[RS_SQ  + c] * (1.f/3136.f) - ms*ms;
  float ss = gs[c] * rsqrtf(vs + 1e-5f);
  float hs = bs[c] - ms*ss;
  float v = fmaf(l2pre[idx], s2, h2) + fmaf(rpre[idx], ss, hs);
  dst[idx] = v > 0.f ? v : 0.f;
}

__global__ void xbar_kernel(const float* __restrict__ res, float* __restrict__ xbar) {
  int b = blockIdx.x, c = threadIdx.x;
  const float* src = res + ((size_t)b*256 + c) * 49;
  float s = 0.f;
  for (int i = 0; i < 49; ++i) s += src[i];
  xbar[b*256 + c] = s * (1.f/49.f);
}

__global__ void u_kernel(const float* __restrict__ wv, const float* __restrict__ xbar,
                         float* __restrict__ u) {
  int b = blockIdx.y;
  int e = blockIdx.x * 256 + threadIdx.x;
  __shared__ float xs[256];
  xs[threadIdx.x] = xbar[b*256 + threadIdx.x];
  __syncthreads();
  const float* wr = wv + (size_t)e * 256;
  float s = 0.f;
  for (int c = 0; c < 256; ++c) s = fmaf(wr[c], xs[c], s);
  u[b*1024 + e] = s;
}

__global__ void head_kernel(const float* __restrict__ wo, const float* __restrict__ bo,
                            const float* __restrict__ u, const float* __restrict__ fcw,
                            const float* __restrict__ fcb, float* __restrict__ out) {
  int b = blockIdx.x, t = threadIdx.x;
  __shared__ float us[1024];
  __shared__ float zs[256];
  for (int i = t; i < 1024; i += 256) us[i] = u[b*1024 + i];
  __syncthreads();
  float z = bo[t];
  const float* wr = wo + (size_t)t * 1024;
  for (int e = 0; e < 1024; ++e) z = fmaf(wr[e], us[e], z);
  zs[t] = z;
  __syncthreads();
  if (t < 50) {
    float s = fcb[t];
    const float* fr = fcw + t*256;
    for (int o = 0; o < 256; ++o) s = fmaf(fr[o], zs[o], s);
    out[b*50 + t] = s;
  }
}

// ---------------- launch ----------------
extern "C" void kernel_launch(void* const* d_in, const int* in_sizes, int n_in,
                              void* d_out, int out_size, void* d_ws, size_t ws_size,
                              hipStream_t stream) {
  const float* imgs = (const float*)d_in[0];
  const float* a1f1 = (const float*)d_in[1];
  const float* a1f2 = (const float*)d_in[2];
  const float* a1b  = (const float*)d_in[3];
  const float* dy1  = (const float*)d_in[4];
  const float* bn1g = (const float*)d_in[5];
  const float* bn1b = (const float*)d_in[6];
  const float* a2f1 = (const float*)d_in[7];
  const float* a2f2 = (const float*)d_in[8];
  const float* a2b  = (const float*)d_in[9];
  const float* dy2  = (const float*)d_in[10];
  const float* bn2g = (const float*)d_in[11];
  const float* bn2b = (const float*)d_in[12];
  const float* rc1w = (const float*)d_in[13];
  const float* rb1g = (const float*)d_in[14];
  const float* rb1b = (const float*)d_in[15];
  const float* rc2w = (const float*)d_in[16];
  const float* rb2g = (const float*)d_in[17];
  const float* rb2b = (const float*)d_in[18];
  const float* rsw  = (const float*)d_in[19];
  const float* rbsg = (const float*)d_in[20];
  const float* rbsb = (const float*)d_in[21];
  // d_in[22]=wq, d_in[23]=wk unused (softmax over k sums to 1 -> attention == identity on v)
  const float* wv_  = (const float*)d_in[24];
  const float* wo_  = (const float*)d_in[25];
  const float* bo_  = (const float*)d_in[26];
  const float* fcw  = (const float*)d_in[27];
  const float* fcb  = (const float*)d_in[28];
  float* out = (float*)d_out;

  char* ws = (char*)d_ws;
  unsigned short* out1 = (unsigned short*)(ws + OFF_OUT1);
  float* out2  = (float*)(ws + OFF_OUT2);
  float* pool1 = (float*)(ws + OFF_POOL1);
  float* pool2 = (float*)(ws + OFF_POOL2);
  float* w1    = (float*)(ws + OFF_W1);
  float* w2    = (float*)(ws + OFF_W2);
  float* l1pre = (float*)(ws + OFF_L1PRE);
  float* l1    = (float*)(ws + OFF_L1);
  float* l2pre = (float*)(ws + OFF_L2PRE);
  float* rpre  = (float*)(ws + OFF_RPRE);
  float* res   = (float*)(ws + OFF_RES);
  float* stats = (float*)(ws + OFF_STATS);
  float* attn1 = (float*)(ws + OFF_ATTN1);
  float* attn2 = (float*)(ws + OFF_ATTN2);
  float* xbar  = (float*)(ws + OFF_XBAR);
  float* u     = (float*)(ws + OFF_U);

  hipMemsetAsync(stats, 0, STATS_N * sizeof(float), stream);

  attn1_kernel<<<64, 256, 0, stream>>>(imgs, a1f1, a1f2, a1b, attn1);
  agg_w_kernel<<<dim3(37, 64), 256, 0, stream>>>(attn1, dy1, w1, 9408);
  conv1_kernel<<<dim3(28, 64), 256, 0, stream>>>(imgs, w1, out1, stats);
  bn_pool1_kernel<<<50176, 256, 0, stream>>>(out1, stats, bn1g, bn1b, pool1);

  attn2_kernel<<<64, 256, 0, stream>>>(pool1, a2f1, a2f2, a2b, attn2);
  agg_w_kernel<<<dim3(288, 64), 256, 0, stream>>>(attn2, dy2, w2, 73728);
  conv2_kernel<<<dim3(14, 64), 256, 0, stream>>>(pool1, w2, out2, stats);
  bn_pool2_kernel<<<6272, 256, 0, stream>>>(out2, stats, bn2g, bn2b, pool2);

  res_conv1_kernel<<<dim3(256, 64), 64, 0, stream>>>(pool2, rc1w, l1pre, stats);
  bn_relu_kernel<<<3136, 256, 0, stream>>>(l1pre, stats, rb1g, rb1b, l1);
  res_conv2_kernel<<<dim3(256, 64), 64, 0, stream>>>(l1, rc2w, l2pre, stats);
  res_short_kernel<<<dim3(256, 64), 64, 0, stream>>>(pool2, rsw, rpre, stats);
  res_merge_kernel<<<3136, 256, 0, stream>>>(l2pre, rpre, stats, rb2g, rb2b, rbsg, rbsb, res);

  xbar_kernel<<<64, 256, 0, stream>>>(res, xbar);
  u_kernel<<<dim3(4, 64), 256, 0, stream>>>(wv_, xbar, u);
  head_kernel<<<64, 256, 0, stream>>>(wo_, bo_, u, fcw, fcb, out);
}

// Round 4
// 1312.531 us; speedup vs baseline: 11.6176x; 1.9348x over previous
//
#include <hip/hip_runtime.h>
#include <hip/hip_bf16.h>

#define DEV static __device__ __forceinline__

// ---------------- helpers ----------------
DEV float wred(float v) {
#pragma unroll
  for (int off = 32; off > 0; off >>= 1) v += __shfl_down(v, off, 64);
  return v;
}

DEV unsigned short f2bf(float f) {
  union { float f; unsigned u; } a; a.f = f;
  unsigned u = a.u;
  unsigned lsb = (u >> 16) & 1u;
  u += 0x7fffu + lsb;            // round-to-nearest-even
  return (unsigned short)(u >> 16);
}
DEV float bf2f(unsigned short us) {
  union { unsigned u; float f; } a; a.u = ((unsigned)us) << 16;
  return a.f;
}

// ---------------- ws layout (bytes) ----------------
// LIFETIME NOTE: out1 (bf16) covers [0, 102760448) until bn_pool1 consumes it.
// wt1/wt2/wts live inside that range -> their producer kernels MUST launch
// after bn_pool1 (they are only needed by the residual block).
#define OFF_OUT1   ((size_t)0)           // bf16 [64,64,112,112]
#define OFF_OUT2   ((size_t)0)           // f32  [64,128,28,28]  (reuses OUT1 after pool1)
#define OFF_POOL2  ((size_t)25690112)    // f32  [64,128,14,14]
#define OFF_W2     ((size_t)32112640)    // f32  [64,128,64,3,3] -> end 50987008
#define OFF_WT1    ((size_t)50987008)    // f32  [1152,256]   (res_conv1 W^T)
#define OFF_WT2    ((size_t)52166656)    // f32  [2304,256]   (res_conv2 W^T)
#define OFF_WTS    ((size_t)54525952)    // f32  [128,256]    (res_short W^T)
#define OFF_L1PRE  ((size_t)54657024)    // f32  2 slabs x [64,256,7,7]
#define OFF_L1     ((size_t)61079552)    // f32  [64,256,7,7]
#define OFF_L2PRE  ((size_t)64290816)    // f32  4 slabs x [64,256,7,7]
#define OFF_RPRE   ((size_t)77135872)    // f32  2 slabs x [64,256,7,7]
#define OFF_RES    ((size_t)83558400)    // f32  [64,256,7,7]
#define OFF_POOL1  ((size_t)102760448)   // f32  [64,64,56,56]
#define OFF_W1     ((size_t)154140672)   // f32  [64,64,3,7,7]
#define OFF_STATS  ((size_t)156549120)   // 1920 f32
#define OFF_ATTN1  (OFF_STATS + 8192)
#define OFF_ATTN2  (OFF_ATTN1 + 2048)
#define OFF_XBAR   (OFF_ATTN2 + 2048)    // [64,256] f32
#define OFF_U      (OFF_XBAR + 65536)    // [64,1024] f32

#define SLAB 802816                      // 64*256*49 elements

#define S1_SUM 0
#define S1_SQ  64
#define S2_SUM 128
#define S2_SQ  256
#define R1_SUM 384
#define R1_SQ  640
#define R2_SUM 896
#define R2_SQ  1152
#define RS_SUM 1408
#define RS_SQ  1664
#define STATS_N 1920

// ---------------- attention MLPs ----------------
__global__ void attn1_kernel(const float* __restrict__ imgs,
                             const float* __restrict__ fc1w,   // [8,3]
                             const float* __restrict__ fc2w,   // [8,8]
                             const float* __restrict__ fc2b,   // [8]
                             float* __restrict__ attn) {       // [64,8]
  int b = blockIdx.x, tid = threadIdx.x, wid = tid >> 6, lane = tid & 63;
  __shared__ float pooled[3];
  const float* x = imgs + (size_t)b * 150528;
  if (wid < 3) {
    const float4* src = (const float4*)(x + wid * 50176);   // 12544 float4
    float s = 0.f;
    for (int i = lane; i < 12544; i += 64) {
      float4 v = src[i];
      s += v.x + v.y + v.z + v.w;
    }
    s = wred(s);
    if (lane == 0) pooled[wid] = s * (1.f / 50176.f);
  }
  __syncthreads();
  if (tid == 0) {
    float h[8];
#pragma unroll
    for (int j = 0; j < 8; ++j) {
      float a = fc1w[j*3+0]*pooled[0] + fc1w[j*3+1]*pooled[1] + fc1w[j*3+2]*pooled[2];
      h[j] = a > 0.f ? a : 0.f;
    }
    float lg[8], mx = -1e30f;
#pragma unroll
    for (int k = 0; k < 8; ++k) {
      float a = fc2b[k];
#pragma unroll
      for (int j = 0; j < 8; ++j) a = fmaf(fc2w[k*8+j], h[j], a);
      lg[k] = a; mx = fmaxf(mx, a);
    }
    float den = 0.f;
#pragma unroll
    for (int k = 0; k < 8; ++k) { lg[k] = expf(lg[k]-mx); den += lg[k]; }
    float inv = 1.f/den;
#pragma unroll
    for (int k = 0; k < 8; ++k) attn[b*8+k] = lg[k]*inv;
  }
}

__global__ void attn2_kernel(const float* __restrict__ pool1,
                             const float* __restrict__ fc1w,   // [17,64]
                             const float* __restrict__ fc2w,   // [8,17]
                             const float* __restrict__ fc2b,   // [8]
                             float* __restrict__ attn) {       // [64,8]
  int b = blockIdx.x, tid = threadIdx.x, wid = tid >> 6, lane = tid & 63;
  __shared__ float pooled[64];
  const float* x = pool1 + (size_t)b * 64 * 3136;
  for (int c = wid; c < 64; c += 4) {
    const float4* src = (const float4*)(x + (size_t)c * 3136);  // 784 float4
    float s = 0.f;
    for (int i = lane; i < 784; i += 64) {
      float4 v = src[i];
      s += v.x + v.y + v.z + v.w;
    }
    s = wred(s);
    if (lane == 0) pooled[c] = s * (1.f/3136.f);
  }
  __syncthreads();
  if (tid == 0) {
    float h[17];
    for (int j = 0; j < 17; ++j) {
      float a = 0.f;
      for (int c = 0; c < 64; ++c) a = fmaf(fc1w[j*64+c], pooled[c], a);
      h[j] = a > 0.f ? a : 0.f;
    }
    float lg[8], mx = -1e30f;
    for (int k = 0; k < 8; ++k) {
      float a = fc2b[k];
      for (int j = 0; j < 17; ++j) a = fmaf(fc2w[k*17+j], h[j], a);
      lg[k] = a; mx = fmaxf(mx, a);
    }
    float den = 0.f;
    for (int k = 0; k < 8; ++k) { lg[k] = expf(lg[k]-mx); den += lg[k]; }
    float inv = 1.f/den;
    for (int k = 0; k < 8; ++k) attn[b*8+k] = lg[k]*inv;
  }
}

// w[b,i] = sum_k attn[b,k] * dyw[k,i]
__global__ void agg_w_kernel(const float* __restrict__ attn, const float* __restrict__ dyw,
                             float* __restrict__ w, int per) {
  int b = blockIdx.y;
  int i = blockIdx.x * 256 + threadIdx.x;
  if (i >= per) return;
  float s = 0.f;
#pragma unroll
  for (int k = 0; k < 8; ++k) s = fmaf(attn[b*8+k], dyw[(size_t)k*per + i], s);
  w[(size_t)b*per + i] = s;
}

// wT[k][oc] = w[oc][k]
__global__ void wt_kernel(const float* __restrict__ w, float* __restrict__ wT,
                          int OC, int K) {
  int i = blockIdx.x * 256 + threadIdx.x;
  if (i >= OC * K) return;
  int oc = i / K, k = i - oc * K;
  wT[(size_t)k * OC + oc] = w[i];
}

// ---------------- conv1: [3,224,224] -> [64,112,112], k7 s2 p3, per-sample W ----------------
__global__ __launch_bounds__(256) void conv1_kernel(
    const float* __restrict__ imgs, const float* __restrict__ w1,
    unsigned short* __restrict__ out1, float* __restrict__ stats) {
  int tile = blockIdx.x, b = blockIdx.y;
  int t = threadIdx.x, pxg = t & 15, ocg4 = (t >> 4) * 4;
  __shared__ float wlds[9408];   // 147 k x 64 oc (swizzled)
  __shared__ float ilds[2088];   // 9 rows x 232
  const float* wp = w1 + (size_t)b * 9408;
  for (int i = t; i < 9408; i += 256) {
    int oc = i / 147, k = i - oc * 147;
    wlds[(k << 6) + ((oc + 4 * k) & 63)] = wp[i];
  }
  const float* img = imgs + (size_t)b * 150528;
  float lsum[4] = {0.f,0.f,0.f,0.f}, lsq[4] = {0.f,0.f,0.f,0.f};
#pragma unroll 1
  for (int oy2 = 0; oy2 < 2; ++oy2) {
    float acc[2][7][4];
#pragma unroll
    for (int ol = 0; ol < 2; ++ol)
#pragma unroll
      for (int j = 0; j < 7; ++j)
#pragma unroll
        for (int q = 0; q < 4; ++q) acc[ol][j][q] = 0.f;
    int iyb = tile * 8 + oy2 * 4 - 3;
#pragma unroll 1
    for (int c = 0; c < 3; ++c) {
      __syncthreads();
      for (int i = t; i < 2088; i += 256) {
        int r = i / 232, p = i - r * 232;
        int iy = iyb + r, x = p - 3;
        float v = 0.f;
        if ((unsigned)iy < 224u && (unsigned)x < 224u) v = img[c * 50176 + iy * 224 + x];
        ilds[i] = v;
      }
      __syncthreads();
#pragma unroll 1
      for (int ky = 0; ky < 7; ++ky) {
        float rA[20], rB[20];
        const float2* pA = (const float2*)&ilds[ky * 232 + 14 * pxg];
        const float2* pB = (const float2*)&ilds[(ky + 2) * 232 + 14 * pxg];
#pragma unroll
        for (int m = 0; m < 10; ++m) {
          float2 v = pA[m]; rA[2*m] = v.x; rA[2*m+1] = v.y;
          float2 u = pB[m]; rB[2*m] = u.x; rB[2*m+1] = u.y;
        }
#pragma unroll
        for (int kx = 0; kx < 7; ++kx) {
          int k = c * 49 + ky * 7 + kx;
          const float4 w = *(const float4*)&wlds[(k << 6) + ((ocg4 + 4 * k) & 63)];
#pragma unroll
          for (int j = 0; j < 7; ++j) {
            float a = rA[2*j + kx], bb = rB[2*j + kx];
            acc[0][j][0] = fmaf(a, w.x, acc[0][j][0]);
            acc[0][j][1] = fmaf(a, w.y, acc[0][j][1]);
            acc[0][j][2] = fmaf(a, w.z, acc[0][j][2]);
            acc[0][j][3] = fmaf(a, w.w, acc[0][j][3]);
            acc[1][j][0] = fmaf(bb, w.x, acc[1][j][0]);
            acc[1][j][1] = fmaf(bb, w.y, acc[1][j][1]);
            acc[1][j][2] = fmaf(bb, w.z, acc[1][j][2]);
            acc[1][j][3] = fmaf(bb, w.w, acc[1][j][3]);
          }
        }
      }
    }
    int oy0 = tile * 4 + oy2 * 2, ox0 = pxg * 7;
#pragma unroll
    for (int ol = 0; ol < 2; ++ol) {
      unsigned short* op = out1 + ((size_t)b * 64 + ocg4) * 12544 + (oy0 + ol) * 112 + ox0;
#pragma unroll
      for (int q = 0; q < 4; ++q) {
#pragma unroll
        for (int j = 0; j < 7; ++j) {
          float v = acc[ol][j][q];
          op[q * 12544 + j] = f2bf(v);
          lsum[q] += v; lsq[q] += v * v;
        }
      }
    }
  }
#pragma unroll
  for (int q = 0; q < 4; ++q) {
#pragma unroll
    for (int off = 1; off < 16; off <<= 1) {
      lsum[q] += __shfl_xor(lsum[q], off, 64);
      lsq[q]  += __shfl_xor(lsq[q],  off, 64);
    }
  }
  if ((t & 15) == 0) {
#pragma unroll
    for (int q = 0; q < 4; ++q) {
      atomicAdd(&stats[S1_SUM + ocg4 + q], lsum[q]);
      atomicAdd(&stats[S1_SQ  + ocg4 + q], lsq[q]);
    }
  }
}

// ---------------- bn1 + maxpool3 s2 p1 ----------------
__global__ void bn_pool1_kernel(const unsigned short* __restrict__ out1,
                                const float* __restrict__ stats,
                                const float* __restrict__ g, const float* __restrict__ bt,
                                float* __restrict__ pool1) {
  int idx = blockIdx.x * 256 + threadIdx.x;
  if (idx >= 12845056) return;
  int x = idx % 56;
  int y = (idx / 56) % 56;
  int bc = idx / 3136;
  int c = bc & 63;
  float mean = stats[S1_SUM + c] * (1.f/802816.f);
  float var  = stats[S1_SQ  + c] * (1.f/802816.f) - mean*mean;
  float scale = g[c] * rsqrtf(var + 1e-5f);
  float shift = bt[c] - mean * scale;
  const unsigned short* src = out1 + (size_t)bc * 12544;
  float m = -3.4e38f;
#pragma unroll
  for (int dy = -1; dy <= 1; ++dy) {
    int iy = 2*y + dy;
    if ((unsigned)iy >= 112u) continue;
#pragma unroll
    for (int dx = -1; dx <= 1; ++dx) {
      int ix = 2*x + dx;
      if ((unsigned)ix >= 112u) continue;
      float v = bf2f(src[iy*112 + ix]);
      m = fmaxf(m, fmaf(v, scale, shift));
    }
  }
  pool1[idx] = m;
}

// ---------------- conv2: [64,56,56] -> [128,28,28], k3 s2 p1, per-sample W ----------------
__global__ __launch_bounds__(256) void conv2_kernel(
    const float* __restrict__ pool1, const float* __restrict__ w2,
    float* __restrict__ out2, float* __restrict__ stats) {
  int bx = blockIdx.x, b = blockIdx.y;
  int och = bx & 1, T = bx >> 1;
  int t = threadIdx.x, pxg = t & 15, ocg4 = (t >> 4) * 4;
  int rr = pxg >> 2, cx = pxg & 3;
  __shared__ float wl[4608];   // 72 k x 64 oc (swizzled)
  __shared__ float il[4176];   // 8 ch x 9 rows x 58
  const float* in = pool1 + (size_t)b * 200704;
  const float* wp = w2 + ((size_t)b * 128 + och * 64) * 576;
  float acc[7][4];
#pragma unroll
  for (int j = 0; j < 7; ++j)
#pragma unroll
    for (int q = 0; q < 4; ++q) acc[j][q] = 0.f;
  int iyb = T * 8 - 1;
#pragma unroll 1
  for (int chunk = 0; chunk < 8; ++chunk) {
    __syncthreads();
    int c0 = chunk * 8;
    for (int i = t; i < 4608; i += 256) {
      int oc = i / 72, kc = i - oc * 72;
      wl[kc * 64 + ((oc + 4 * kc) & 63)] = wp[oc * 576 + c0 * 9 + kc];
    }
    for (int i = t; i < 4176; i += 256) {
      int cc = i / 522, rem = i - cc * 522, r = rem / 58, p = rem - r * 58;
      int iy = iyb + r, x = p - 1;
      float v = 0.f;
      if ((unsigned)iy < 56u && (unsigned)x < 56u) v = in[(c0 + cc) * 3136 + iy * 56 + x];
      il[i] = v;
    }
    __syncthreads();
#pragma unroll 1
    for (int cc = 0; cc < 8; ++cc) {
#pragma unroll
      for (int ky = 0; ky < 3; ++ky) {
        int r = 2 * rr + ky;
        float rA[16];
        const float2* pA = (const float2*)&il[(cc * 9 + r) * 58 + 14 * cx];
#pragma unroll
        for (int m = 0; m < 8; ++m) { float2 v = pA[m]; rA[2*m] = v.x; rA[2*m+1] = v.y; }
#pragma unroll
        for (int kx = 0; kx < 3; ++kx) {
          int kc = cc * 9 + ky * 3 + kx;
          const float4 w = *(const float4*)&wl[(kc << 6) + ((ocg4 + 4 * kc) & 63)];
#pragma unroll
          for (int j = 0; j < 7; ++j) {
            float a = rA[2*j + kx];
            acc[j][0] = fmaf(a, w.x, acc[j][0]);
            acc[j][1] = fmaf(a, w.y, acc[j][1]);
            acc[j][2] = fmaf(a, w.z, acc[j][2]);
            acc[j][3] = fmaf(a, w.w, acc[j][3]);
          }
        }
      }
    }
  }
  int oy = T * 4 + rr, ox0 = cx * 7;
  int ocb = och * 64 + ocg4;
  float* op = out2 + ((size_t)b * 128 + ocb) * 784 + oy * 28 + ox0;
  float ls[4] = {0.f,0.f,0.f,0.f}, lq[4] = {0.f,0.f,0.f,0.f};
#pragma unroll
  for (int q = 0; q < 4; ++q) {
#pragma unroll
    for (int j = 0; j < 7; ++j) {
      float v = acc[j][q];
      op[q * 784 + j] = v;
      ls[q] += v; lq[q] += v * v;
    }
  }
#pragma unroll
  for (int q = 0; q < 4; ++q) {
#pragma unroll
    for (int off = 1; off < 16; off <<= 1) {
      ls[q] += __shfl_xor(ls[q], off, 64);
      lq[q] += __shfl_xor(lq[q], off, 64);
    }
  }
  if ((t & 15) == 0) {
#pragma unroll
    for (int q = 0; q < 4; ++q) {
      atomicAdd(&stats[S2_SUM + ocb + q], ls[q]);
      atomicAdd(&stats[S2_SQ  + ocb + q], lq[q]);
    }
  }
}

// ---------------- bn2 + maxpool3 s2 p1 ----------------
__global__ void bn_pool2_kernel(const float* __restrict__ out2,
                                const float* __restrict__ stats,
                                const float* __restrict__ g, const float* __restrict__ bt,
                                float* __restrict__ pool2) {
  int idx = blockIdx.x * 256 + threadIdx.x;
  if (idx >= 1605632) return;
  int x = idx % 14;
  int y = (idx / 14) % 14;
  int bc = idx / 196;
  int c = bc & 127;
  float mean = stats[S2_SUM + c] * (1.f/50176.f);
  float var  = stats[S2_SQ  + c] * (1.f/50176.f) - mean*mean;
  float scale = g[c] * rsqrtf(var + 1e-5f);
  float shift = bt[c] - mean * scale;
  const float* src = out2 + (size_t)bc * 784;
  float m = -3.4e38f;
#pragma unroll
  for (int dy = -1; dy <= 1; ++dy) {
    int iy = 2*y + dy;
    if ((unsigned)iy >= 28u) continue;
#pragma unroll
    for (int dx = -1; dx <= 1; ++dx) {
      int ix = 2*x + dx;
      if ((unsigned)ix >= 28u) continue;
      m = fmaxf(m, fmaf(src[iy*28 + ix], scale, shift));
    }
  }
  pool2[idx] = m;
}

// ---------------- residual convs (split-K, slab outputs, wT weights) ----------------
// res_conv1: pool2 [b,128,14,14] -> slabs[kq<2] of [b,256,7,7]; 3x3 s2 p1.
__global__ __launch_bounds__(128) void res_conv1_kernel(
    const float* __restrict__ pool2, const float* __restrict__ wT,
    float* __restrict__ outp) {
  int bx = blockIdx.x, b = blockIdx.y;
  int ocq = bx & 3, kq = bx >> 2;
  int t = threadIdx.x, row = t & 7, ocg4 = (t >> 3) * 4;
  __shared__ float il[2400];   // 8 ch x 15 rows x 20
  __shared__ float wl[4608];   // 72 kc x 64 oc (swizzled)
  const float* in = pool2 + (size_t)b * 25088 + (kq * 64) * 196;
  float acc[7][4];
#pragma unroll
  for (int j = 0; j < 7; ++j)
#pragma unroll
    for (int q = 0; q < 4; ++q) acc[j][q] = 0.f;
#pragma unroll 1
  for (int chunk = 0; chunk < 8; ++chunk) {
    __syncthreads();
    int c0 = chunk * 8;
    int kbase = kq * 576 + chunk * 72;
    for (int i = t; i < 2400; i += 128) {
      int cc = i / 300, rem = i - cc * 300, r = rem / 20, x = rem - r * 20;
      int iy = r - 1, ix = x - 1;
      float v = 0.f;
      if ((unsigned)iy < 14u && (unsigned)ix < 14u) v = in[(c0 + cc) * 196 + iy * 14 + ix];
      il[i] = v;
    }
    for (int i = t; i < 4608; i += 128) {
      int kc = i >> 6, oc = i & 63;
      wl[(kc << 6) + ((oc + 4 * (kc & 15)) & 63)] = wT[(size_t)(kbase + kc) * 256 + ocq * 64 + oc];
    }
    __syncthreads();
    if (row < 7) {
#pragma unroll 1
      for (int cc = 0; cc < 8; ++cc) {
#pragma unroll
        for (int ky = 0; ky < 3; ++ky) {
          int r = 2 * row + ky;
          float rv[16];
          const float4* pA = (const float4*)&il[cc * 300 + r * 20];
#pragma unroll
          for (int m = 0; m < 4; ++m) {
            float4 v = pA[m]; rv[4*m]=v.x; rv[4*m+1]=v.y; rv[4*m+2]=v.z; rv[4*m+3]=v.w;
          }
#pragma unroll
          for (int kx = 0; kx < 3; ++kx) {
            int kc = cc * 9 + ky * 3 + kx;
            const float4 w = *(const float4*)&wl[(kc << 6) + ((ocg4 + 4 * (kc & 15)) & 63)];
#pragma unroll
            for (int j = 0; j < 7; ++j) {
              float a = rv[2*j + kx];
              acc[j][0] = fmaf(a, w.x, acc[j][0]);
              acc[j][1] = fmaf(a, w.y, acc[j][1]);
              acc[j][2] = fmaf(a, w.z, acc[j][2]);
              acc[j][3] = fmaf(a, w.w, acc[j][3]);
            }
          }
        }
      }
    }
  }
  if (row < 7) {
    float* op = outp + (size_t)kq * SLAB + ((size_t)b * 256 + ocq * 64 + ocg4) * 49 + row * 7;
#pragma unroll
    for (int q = 0; q < 4; ++q)
#pragma unroll
      for (int j = 0; j < 7; ++j) op[q * 49 + j] = acc[j][q];
  }
}

// res_conv2: l1 [b,256,7,7] -> slabs[kq<4] of [b,256,7,7]; 3x3 s1 p1.
__global__ __launch_bounds__(128) void res_conv2_kernel(
    const float* __restrict__ l1, const float* __restrict__ wT,
    float* __restrict__ outp) {
  int bx = blockIdx.x, b = blockIdx.y;
  int ocq = bx & 3, kq = bx >> 2;
  int t = threadIdx.x, row = t & 7, ocg4 = (t >> 3) * 4;
  __shared__ float il[864];    // 8 ch x 9 rows x 12
  __shared__ float wl[4608];   // 72 kc x 64 oc (swizzled)
  const float* in = l1 + (size_t)b * 12544 + (kq * 64) * 49;
  float acc[7][4];
#pragma unroll
  for (int j = 0; j < 7; ++j)
#pragma unroll
    for (int q = 0; q < 4; ++q) acc[j][q] = 0.f;
#pragma unroll 1
  for (int chunk = 0; chunk < 8; ++chunk) {
    __syncthreads();
    int c0 = chunk * 8;
    int kbase = kq * 576 + chunk * 72;
    for (int i = t; i < 864; i += 128) {
      int cc = i / 108, rem = i - cc * 108, r = rem / 12, x = rem - r * 12;
      int iy = r - 1, ix = x - 1;
      float v = 0.f;
      if ((unsigned)iy < 7u && (unsigned)ix < 7u) v = in[(c0 + cc) * 49 + iy * 7 + ix];
      il[i] = v;
    }
    for (int i = t; i < 4608; i += 128) {
      int kc = i >> 6, oc = i & 63;
      wl[(kc << 6) + ((oc + 4 * (kc & 15)) & 63)] = wT[(size_t)(kbase + kc) * 256 + ocq * 64 + oc];
    }
    __syncthreads();
    if (row < 7) {
#pragma unroll 1
      for (int cc = 0; cc < 8; ++cc) {
#pragma unroll
        for (int ky = 0; ky < 3; ++ky) {
          int r = row + ky;
          float rv[12];
          const float4* pA = (const float4*)&il[cc * 108 + r * 12];
#pragma unroll
          for (int m = 0; m < 3; ++m) {
            float4 v = pA[m]; rv[4*m]=v.x; rv[4*m+1]=v.y; rv[4*m+2]=v.z; rv[4*m+3]=v.w;
          }
#pragma unroll
          for (int kx = 0; kx < 3; ++kx) {
            int kc = cc * 9 + ky * 3 + kx;
            const float4 w = *(const float4*)&wl[(kc << 6) + ((ocg4 + 4 * (kc & 15)) & 63)];
#pragma unroll
            for (int j = 0; j < 7; ++j) {
              float a = rv[j + kx];
              acc[j][0] = fmaf(a, w.x, acc[j][0]);
              acc[j][1] = fmaf(a, w.y, acc[j][1]);
              acc[j][2] = fmaf(a, w.z, acc[j][2]);
              acc[j][3] = fmaf(a, w.w, acc[j][3]);
            }
          }
        }
      }
    }
  }
  if (row < 7) {
    float* op = outp + (size_t)kq * SLAB + ((size_t)b * 256 + ocq * 64 + ocg4) * 49 + row * 7;
#pragma unroll
    for (int q = 0; q < 4; ++q)
#pragma unroll
      for (int j = 0; j < 7; ++j) op[q * 49 + j] = acc[j][q];
  }
}

// res_short: pool2 [b,128,14,14] -> slabs[kq<2] of [b,256,7,7]; 1x1 s2.
__global__ __launch_bounds__(128) void res_short_kernel(
    const float* __restrict__ pool2, const float* __restrict__ wT,
    float* __restrict__ outp) {
  int bx = blockIdx.x, b = blockIdx.y;
  int ocq = bx & 3, kq = bx >> 2;
  int t = threadIdx.x, row = t & 7, ocg4 = (t >> 3) * 4;
  __shared__ float il[448];    // 8 ch x 7 rows x 8 (decimated)
  __shared__ float wl[512];    // 8 kc x 64 oc (swizzled)
  const float* in = pool2 + (size_t)b * 25088 + (kq * 64) * 196;
  float acc[7][4];
#pragma unroll
  for (int j = 0; j < 7; ++j)
#pragma unroll
    for (int q = 0; q < 4; ++q) acc[j][q] = 0.f;
#pragma unroll 1
  for (int chunk = 0; chunk < 8; ++chunk) {
    __syncthreads();
    int c0 = chunk * 8;
    int kbase = kq * 64 + chunk * 8;
    for (int i = t; i < 448; i += 128) {
      int cc = i / 56, rem = i - cc * 56, r = rem / 8, x = rem - r * 8;
      float v = 0.f;
      if (x < 7) v = in[(c0 + cc) * 196 + r * 28 + x * 2];
      il[i] = v;
    }
    for (int i = t; i < 512; i += 128) {
      int kc = i >> 6, oc = i & 63;
      wl[(kc << 6) + ((oc + 4 * kc) & 63)] = wT[(size_t)(kbase + kc) * 256 + ocq * 64 + oc];
    }
    __syncthreads();
    if (row < 7) {
#pragma unroll
      for (int cc = 0; cc < 8; ++cc) {
        float rv[8];
        const float4* pA = (const float4*)&il[cc * 56 + row * 8];
#pragma unroll
        for (int m = 0; m < 2; ++m) {
          float4 v = pA[m]; rv[4*m]=v.x; rv[4*m+1]=v.y; rv[4*m+2]=v.z; rv[4*m+3]=v.w;
        }
        const float4 w = *(const float4*)&wl[(cc << 6) + ((ocg4 + 4 * cc) & 63)];
#pragma unroll
        for (int j = 0; j < 7; ++j) {
          float a = rv[j];
          acc[j][0] = fmaf(a, w.x, acc[j][0]);
          acc[j][1] = fmaf(a, w.y, acc[j][1]);
          acc[j][2] = fmaf(a, w.z, acc[j][2]);
          acc[j][3] = fmaf(a, w.w, acc[j][3]);
        }
      }
    }
  }
  if (row < 7) {
    float* op = outp + (size_t)kq * SLAB + ((size_t)b * 256 + ocq * 64 + ocg4) * 49 + row * 7;
#pragma unroll
    for (int q = 0; q < 4; ++q)
#pragma unroll
      for (int j = 0; j < 7; ++j) op[q * 49 + j] = acc[j][q];
  }
}

// per-channel sum/sq over summed slabs
__global__ void stats_slab_kernel(const float* __restrict__ s, int nslab,
                                  float* __restrict__ stats, int sumbase, int sqbase) {
  int oc = blockIdx.x, t = threadIdx.x;
  float sum = 0.f, sq = 0.f;
  for (int i = t; i < 3136; i += 256) {
    int b = i / 49, p = i - b * 49;
    size_t idx = ((size_t)b * 256 + oc) * 49 + p;
    float v = 0.f;
    for (int k = 0; k < nslab; ++k) v += s[(size_t)k * SLAB + idx];
    sum += v; sq += v * v;
  }
  sum = wred(sum); sq = wred(sq);
  __shared__ float bs[4], bq[4];
  int wid = t >> 6;
  if ((t & 63) == 0) { bs[wid] = sum; bq[wid] = sq; }
  __syncthreads();
  if (t == 0) {
    stats[sumbase + oc] = bs[0] + bs[1] + bs[2] + bs[3];
    stats[sqbase + oc]  = bq[0] + bq[1] + bq[2] + bq[3];
  }
}

// l1 = relu(bn(l1pre_slab0 + l1pre_slab1))
__global__ void bn_relu_kernel(const float* __restrict__ src, const float* __restrict__ stats,
                               const float* __restrict__ g, const float* __restrict__ bt,
                               float* __restrict__ dst) {
  int idx = blockIdx.x * 256 + threadIdx.x;
  if (idx >= 802816) return;
  int c = (idx / 49) & 255;
  float mean = stats[R1_SUM + c] * (1.f/3136.f);
  float var  = stats[R1_SQ  + c] * (1.f/3136.f) - mean*mean;
  float scale = g[c] * rsqrtf(var + 1e-5f);
  float shift = bt[c] - mean*scale;
  float v = fmaf(src[idx] + src[SLAB + idx], scale, shift);
  dst[idx] = v > 0.f ? v : 0.f;
}

// res = relu(bn2(sum4 l2pre) + bns(sum2 rpre))
__global__ void res_merge_kernel(const float* __restrict__ l2pre, const float* __restrict__ rpre,
                                 const float* __restrict__ stats,
                                 const float* __restrict__ g2, const float* __restrict__ b2,
                                 const float* __restrict__ gs, const float* __restrict__ bs,
                                 float* __restrict__ dst) {
  int idx = blockIdx.x * 256 + threadIdx.x;
  if (idx >= 802816) return;
  int c = (idx / 49) & 255;
  float m2 = stats[R2_SUM + c] * (1.f/3136.f);
  float v2 = stats[R2_SQ  + c] * (1.f/3136.f) - m2*m2;
  float s2 = g2[c] * rsqrtf(v2 + 1e-5f);
  float h2 = b2[c] - m2*s2;
  float ms = stats[RS_SUM + c] * (1.f/3136.f);
  float vs = stats[RS_SQ  + c] * (1.f/3136.f) - ms*ms;
  float ss = gs[c] * rsqrtf(vs + 1e-5f);
  float hs = bs[c] - ms*ss;
  float l2 = l2pre[idx] + l2pre[SLAB + idx] + l2pre[2*SLAB + idx] + l2pre[3*SLAB + idx];
  float r  = rpre[idx] + rpre[SLAB + idx];
  float v = fmaf(l2, s2, h2) + fmaf(r, ss, hs);
  dst[idx] = v > 0.f ? v : 0.f;
}

__global__ void xbar_kernel(const float* __restrict__ res, float* __restrict__ xbar) {
  int b = blockIdx.x, c = threadIdx.x;
  const float* src = res + ((size_t)b*256 + c) * 49;
  float s = 0.f;
  for (int i = 0; i < 49; ++i) s += src[i];
  xbar[b*256 + c] = s * (1.f/49.f);
}

__global__ void u_kernel(const float* __restrict__ wv, const float* __restrict__ xbar,
                         float* __restrict__ u) {
  int b = blockIdx.y;
  int e = blockIdx.x * 256 + threadIdx.x;
  __shared__ float xs[256];
  xs[threadIdx.x] = xbar[b*256 + threadIdx.x];
  __syncthreads();
  const float* wr = wv + (size_t)e * 256;
  float s = 0.f;
  for (int c = 0; c < 256; ++c) s = fmaf(wr[c], xs[c], s);
  u[b*1024 + e] = s;
}

__global__ void head_kernel(const float* __restrict__ wo, const float* __restrict__ bo,
                            const float* __restrict__ u, const float* __restrict__ fcw,
                            const float* __restrict__ fcb, float* __restrict__ out) {
  int b = blockIdx.x, t = threadIdx.x;
  __shared__ float us[1024];
  __shared__ float zs[256];
  for (int i = t; i < 1024; i += 256) us[i] = u[b*1024 + i];
  __syncthreads();
  float z = bo[t];
  const float* wr = wo + (size_t)t * 1024;
  for (int e = 0; e < 1024; ++e) z = fmaf(wr[e], us[e], z);
  zs[t] = z;
  __syncthreads();
  if (t < 50) {
    float s = fcb[t];
    const float* fr = fcw + t*256;
    for (int o = 0; o < 256; ++o) s = fmaf(fr[o], zs[o], s);
    out[b*50 + t] = s;
  }
}

// ---------------- launch ----------------
extern "C" void kernel_launch(void* const* d_in, const int* in_sizes, int n_in,
                              void* d_out, int out_size, void* d_ws, size_t ws_size,
                              hipStream_t stream) {
  const float* imgs = (const float*)d_in[0];
  const float* a1f1 = (const float*)d_in[1];
  const float* a1f2 = (const float*)d_in[2];
  const float* a1b  = (const float*)d_in[3];
  const float* dy1  = (const float*)d_in[4];
  const float* bn1g = (const float*)d_in[5];
  const float* bn1b = (const float*)d_in[6];
  const float* a2f1 = (const float*)d_in[7];
  const float* a2f2 = (const float*)d_in[8];
  const float* a2b  = (const float*)d_in[9];
  const float* dy2  = (const float*)d_in[10];
  const float* bn2g = (const float*)d_in[11];
  const float* bn2b = (const float*)d_in[12];
  const float* rc1w = (const float*)d_in[13];
  const float* rb1g = (const float*)d_in[14];
  const float* rb1b = (const float*)d_in[15];
  const float* rc2w = (const float*)d_in[16];
  const float* rb2g = (const float*)d_in[17];
  const float* rb2b = (const float*)d_in[18];
  const float* rsw  = (const float*)d_in[19];
  const float* rbsg = (const float*)d_in[20];
  const float* rbsb = (const float*)d_in[21];
  // d_in[22]=wq, d_in[23]=wk unused (softmax over k sums to 1 -> attention == identity on v)
  const float* wv_  = (const float*)d_in[24];
  const float* wo_  = (const float*)d_in[25];
  const float* bo_  = (const float*)d_in[26];
  const float* fcw  = (const float*)d_in[27];
  const float* fcb  = (const float*)d_in[28];
  float* out = (float*)d_out;

  char* ws = (char*)d_ws;
  unsigned short* out1 = (unsigned short*)(ws + OFF_OUT1);
  float* out2  = (float*)(ws + OFF_OUT2);
  float* pool1 = (float*)(ws + OFF_POOL1);
  float* pool2 = (float*)(ws + OFF_POOL2);
  float* w1    = (float*)(ws + OFF_W1);
  float* w2    = (float*)(ws + OFF_W2);
  float* wt1   = (float*)(ws + OFF_WT1);
  float* wt2   = (float*)(ws + OFF_WT2);
  float* wts   = (float*)(ws + OFF_WTS);
  float* l1pre = (float*)(ws + OFF_L1PRE);
  float* l1    = (float*)(ws + OFF_L1);
  float* l2pre = (float*)(ws + OFF_L2PRE);
  float* rpre  = (float*)(ws + OFF_RPRE);
  float* res   = (float*)(ws + OFF_RES);
  float* stats = (float*)(ws + OFF_STATS);
  float* attn1 = (float*)(ws + OFF_ATTN1);
  float* attn2 = (float*)(ws + OFF_ATTN2);
  float* xbar  = (float*)(ws + OFF_XBAR);
  float* u     = (float*)(ws + OFF_U);

  hipMemsetAsync(stats, 0, STATS_N * sizeof(float), stream);

  attn1_kernel<<<64, 256, 0, stream>>>(imgs, a1f1, a1f2, a1b, attn1);
  agg_w_kernel<<<dim3(37, 64), 256, 0, stream>>>(attn1, dy1, w1, 9408);
  conv1_kernel<<<dim3(28, 64), 256, 0, stream>>>(imgs, w1, out1, stats);
  bn_pool1_kernel<<<50176, 256, 0, stream>>>(out1, stats, bn1g, bn1b, pool1);

  // weight transposes for the residual block — MUST come after bn_pool1
  // (wt buffers live inside out1's byte range; see layout note above)
  wt_kernel<<<1152, 256, 0, stream>>>(rc1w, wt1, 256, 1152);
  wt_kernel<<<2304, 256, 0, stream>>>(rc2w, wt2, 256, 2304);
  wt_kernel<<<128, 256, 0, stream>>>(rsw, wts, 256, 128);

  attn2_kernel<<<64, 256, 0, stream>>>(pool1, a2f1, a2f2, a2b, attn2);
  agg_w_kernel<<<dim3(288, 64), 256, 0, stream>>>(attn2, dy2, w2, 73728);
  conv2_kernel<<<dim3(14, 64), 256, 0, stream>>>(pool1, w2, out2, stats);
  bn_pool2_kernel<<<6272, 256, 0, stream>>>(out2, stats, bn2g, bn2b, pool2);

  res_conv1_kernel<<<dim3(8, 64), 128, 0, stream>>>(pool2, wt1, l1pre);
  res_short_kernel<<<dim3(8, 64), 128, 0, stream>>>(pool2, wts, rpre);
  stats_slab_kernel<<<256, 256, 0, stream>>>(l1pre, 2, stats, R1_SUM, R1_SQ);
  bn_relu_kernel<<<3136, 256, 0, stream>>>(l1pre, stats, rb1g, rb1b, l1);
  res_conv2_kernel<<<dim3(16, 64), 128, 0, stream>>>(l1, wt2, l2pre);
  stats_slab_kernel<<<256, 256, 0, stream>>>(l2pre, 4, stats, R2_SUM, R2_SQ);
  stats_slab_kernel<<<256, 256, 0, stream>>>(rpre, 2, stats, RS_SUM, RS_SQ);
  res_merge_kernel<<<3136, 256, 0, stream>>>(l2pre, rpre, stats, rb2g, rb2b, rbsg, rbsb, res);

  xbar_kernel<<<64, 256, 0, stream>>>(res, xbar);
  u_kernel<<<dim3(4, 64), 256, 0, stream>>>(wv_, xbar, u);
  head_kernel<<<64, 256, 0, stream>>>(wo_, bo_, u, fcw, fcb, out);
}